// Round 11
// baseline (212.883 us; speedup 1.0000x reference)
//
#include <hip/hip_runtime.h>
#include <stdint.h>

typedef unsigned short u16;
typedef __attribute__((ext_vector_type(8))) short bf16x8;
typedef __attribute__((ext_vector_type(4))) float f32x4;

#define BATCH 2
#define S_LEN 2048
#define DMODEL 1024
#define NH 16
#define DHEAD 64
#define MTOT 4096
#define QSCALE 0.18033688011112042f /* log2(e)/8 : folds 1/sqrt(DH) and exp->exp2 */
#define PST 72  /* Ps stride u16: 16B-aligned rows; quad offsets {0,16} banks, l15 spread -> writes ~2-way, b128 reads conflict-free */

// async global->LDS, 16B per lane; LDS dest is wave-uniform base + lane*16
#define GL2LDS(g, l) \
  __builtin_amdgcn_global_load_lds((const __attribute__((address_space(1))) void*)(g), \
                                   (__attribute__((address_space(3))) void*)(l), 16, 0, 0)

__device__ __forceinline__ u16 f2bf(float x) {  // RNE
  union { float f; uint32_t u; } v; v.f = x;
  uint32_t r = v.u + 0x7fffu + ((v.u >> 16) & 1u);
  return (u16)(r >> 16);
}
__device__ __forceinline__ u16 f2bf_fast(float x) {  // round-half-up (hot path)
  union { float f; uint32_t u; } v; v.f = x;
  return (u16)((v.u + 0x8000u) >> 16);
}

struct CvtArgs {
  const float* src[5];
  u16* dst[5];
};

// region 0: x (4096 blocks), regions 1..4: weights (1024 blocks each)
__global__ __launch_bounds__(256) void cvt_all(CvtArgs a) {
  int bx = blockIdx.x;
  int region, off;
  if (bx < 4096) { region = 0; off = bx; }
  else { region = 1 + ((bx - 4096) >> 10); off = (bx - 4096) & 1023; }
  const float* s = a.src[region];
  u16* d = a.dst[region];
  int i = (off * 256 + threadIdx.x) * 4;
  float4 v = *(const float4*)(s + i);
  uint2 pk;
  pk.x = (uint32_t)f2bf(v.x) | ((uint32_t)f2bf(v.y) << 16);
  pk.y = (uint32_t)f2bf(v.z) | ((uint32_t)f2bf(v.w) << 16);
  *(uint2*)(d + i) = pk;
}

// ---------------- 128x128 GEMM body, BK=32 (QKV projections) ----------------
// global_load_lds width-16 staging + XOR column swizzle (R10, verified).
// mode 1: bf16 (B,H,S,DH)*scale;  mode 2: bf16 Vt8 (bh, s/8, d, s%8)*scale
__device__ __forceinline__ void gemm_body(const u16* __restrict__ A,
                                          const u16* __restrict__ W,
                                          const float* __restrict__ bias,
                                          void* __restrict__ out,
                                          int mode, float scale) {
  __shared__ u16 As[128 * 32];
  __shared__ u16 Bs[128 * 32];
  const int tid = threadIdx.x;
  const int m0 = blockIdx.y * 128;
  const int n0 = blockIdx.x * 128;
  const int wave = tid >> 6, lane = tid & 63;
  const int wm = (wave >> 1) * 64, wn = (wave & 1) * 64;
  const int quad = lane >> 4, l15 = lane & 15;

  const int row0 = tid >> 2, g0 = ((tid & 3) ^ (row0 & 3)) * 8;
  const int row1 = (tid + 256) >> 2, g1 = ((tid & 3) ^ (row1 & 3)) * 8;
  const int lb0 = wave * 512;
  const int lb1 = 2048 + wave * 512;
  const int xk = (quad ^ (l15 & 3)) * 8;

  f32x4 acc[4][4] = {};

  for (int kt = 0; kt < DMODEL; kt += 32) {
    GL2LDS(A + (size_t)(m0 + row0) * DMODEL + kt + g0, As + lb0);
    GL2LDS(A + (size_t)(m0 + row1) * DMODEL + kt + g1, As + lb1);
    GL2LDS(W + (size_t)(n0 + row0) * DMODEL + kt + g0, Bs + lb0);
    GL2LDS(W + (size_t)(n0 + row1) * DMODEL + kt + g1, Bs + lb1);
    __syncthreads();
    bf16x8 af[4], bfr[4];
#pragma unroll
    for (int bi = 0; bi < 4; ++bi)
      af[bi] = *(const bf16x8*)(&As[(wm + bi * 16 + l15) * 32 + xk]);
#pragma unroll
    for (int bj = 0; bj < 4; ++bj)
      bfr[bj] = *(const bf16x8*)(&Bs[(wn + bj * 16 + l15) * 32 + xk]);
#pragma unroll
    for (int bi = 0; bi < 4; ++bi)
#pragma unroll
      for (int bj = 0; bj < 4; ++bj)
        acc[bi][bj] = __builtin_amdgcn_mfma_f32_16x16x32_bf16(af[bi], bfr[bj], acc[bi][bj], 0, 0, 0);
    __syncthreads();
  }

#pragma unroll
  for (int bi = 0; bi < 4; ++bi) {
#pragma unroll
    for (int bj = 0; bj < 4; ++bj) {
      int n = n0 + wn + bj * 16 + l15;
      float bval = bias[n];
#pragma unroll
      for (int r = 0; r < 4; ++r) {
        int m = m0 + wm + bi * 16 + quad * 4 + r; // C/D layout: row = quad*4+reg, col = lane&15
        float v = (acc[bi][bj][r] + bval) * scale;
        u16 bvu = f2bf(v);
        int b = m >> 11, s = m & 2047;
        int h = n >> 6, d = n & 63;
        size_t bh = (size_t)(b * NH + h);
        if (mode == 1)
          ((u16*)out)[(bh * S_LEN + s) * DHEAD + d] = bvu;
        else
          ((u16*)out)[((bh * 256 + (s >> 3)) * 64 + d) * 8 + (s & 7)] = bvu;
      }
    }
  }
}

struct QKVArgs {
  const u16* w[3];
  const float* b[3];
  u16* o[3];
};

__global__ __launch_bounds__(256) void qkv_gemm(const u16* __restrict__ xb, QKVArgs a) {
  int z = blockIdx.z;
  int mode = (z == 2) ? 2 : 1;
  float scale = (z == 0) ? QSCALE : 1.0f;
  gemm_body(xb, a.w[z], a.b[z], a.o[z], mode, scale);
}

// ---------------- 128x64 GEMM, BK=32 (output projection) ----------------
__global__ __launch_bounds__(256) void out_gemm(const u16* __restrict__ A,
                                                const u16* __restrict__ W,
                                                const float* __restrict__ bias,
                                                float* __restrict__ out) {
  __shared__ u16 As[128 * 32];
  __shared__ u16 Bs[64 * 32];
  const int tid = threadIdx.x;
  const int m0 = blockIdx.y * 128;
  const int n0 = blockIdx.x * 64;
  const int wave = tid >> 6, lane = tid & 63;
  const int wm = (wave >> 1) * 64, wn = (wave & 1) * 32;
  const int quad = lane >> 4, l15 = lane & 15;

  const int row0 = tid >> 2, g0 = ((tid & 3) ^ (row0 & 3)) * 8;
  const int row1 = (tid + 256) >> 2, g1 = ((tid & 3) ^ (row1 & 3)) * 8;
  const int lb0 = wave * 512;
  const int lb1 = 2048 + wave * 512;
  const int xk = (quad ^ (l15 & 3)) * 8;

  f32x4 acc[4][2] = {};

  for (int kt = 0; kt < DMODEL; kt += 32) {
    GL2LDS(A + (size_t)(m0 + row0) * DMODEL + kt + g0, As + lb0);
    GL2LDS(A + (size_t)(m0 + row1) * DMODEL + kt + g1, As + lb1);
    GL2LDS(W + (size_t)(n0 + row0) * DMODEL + kt + g0, Bs + lb0);
    __syncthreads();
    bf16x8 af[4], bfr[2];
#pragma unroll
    for (int bi = 0; bi < 4; ++bi)
      af[bi] = *(const bf16x8*)(&As[(wm + bi * 16 + l15) * 32 + xk]);
#pragma unroll
    for (int bj = 0; bj < 2; ++bj)
      bfr[bj] = *(const bf16x8*)(&Bs[(wn + bj * 16 + l15) * 32 + xk]);
#pragma unroll
    for (int bi = 0; bi < 4; ++bi)
#pragma unroll
      for (int bj = 0; bj < 2; ++bj)
        acc[bi][bj] = __builtin_amdgcn_mfma_f32_16x16x32_bf16(af[bi], bfr[bj], acc[bi][bj], 0, 0, 0);
    __syncthreads();
  }

#pragma unroll
  for (int bi = 0; bi < 4; ++bi) {
#pragma unroll
    for (int bj = 0; bj < 2; ++bj) {
      int n = n0 + wn + bj * 16 + l15;
      float bval = bias[n];
#pragma unroll
      for (int r = 0; r < 4; ++r) {
        int m = m0 + wm + bi * 16 + quad * 4 + r;
        out[(size_t)m * DMODEL + n] = acc[bi][bj][r] + bval;
      }
    }
  }
}

// ---------------- Flash attention ----------------
// One QK/softmax/PV tile step for one 64-row q-tile (wave owns 16 rows).
__device__ __forceinline__ void attn_tile(int qt, int kt, int km,
                                          bf16x8 qf0, bf16x8 qf1,
                                          float* l_part, f32x4* o,
                                          const u16* __restrict__ K,
                                          const u16* __restrict__ V,
                                          u16* __restrict__ Ps,
                                          int wave, int quad, int l15, int xk7) {
  const bool diag = (kt == km);
  const int qg_max = qt * 64 + wave * 16 + 15;
  f32x4 s_acc[8];
#pragma unroll
  for (int bj = 0; bj < 8; ++bj) {
    if (diag && (kt * 128 + bj * 16 > qg_max)) {
      s_acc[bj] = f32x4{-1e30f, -1e30f, -1e30f, -1e30f};
      continue;
    }
    const int krow = (bj * 16 + l15) * 64;
    bf16x8 kf0 = *(const bf16x8*)(&K[krow + ((quad ^ xk7) * 8)]);
    bf16x8 kf1 = *(const bf16x8*)(&K[krow + (((quad + 4) ^ xk7) * 8)]);
    f32x4 t = {0.f, 0.f, 0.f, 0.f};
    t = __builtin_amdgcn_mfma_f32_16x16x32_bf16(qf0, kf0, t, 0, 0, 0);
    t = __builtin_amdgcn_mfma_f32_16x16x32_bf16(qf1, kf1, t, 0, 0, 0);
    s_acc[bj] = t;
  }

  if (diag) { // elementwise causal mask
#pragma unroll
    for (int bj = 0; bj < 8; ++bj) {
      int kg = kt * 128 + bj * 16 + l15;
#pragma unroll
      for (int r = 0; r < 4; ++r) {
        int qg = qt * 64 + wave * 16 + quad * 4 + r;
        if (kg > qg) s_acc[bj][r] = -1e30f;
      }
    }
  }

  // softmax numerator + PV in two 64-column passes (Ps rows wave-private,
  // reused sequentially within the wave -> no barrier)
#pragma unroll
  for (int ph = 0; ph < 2; ++ph) {
    if (diag && (kt * 128 + ph * 64 > qg_max)) continue;
#pragma unroll
    for (int bj2 = 0; bj2 < 4; ++bj2) {
      int bj = ph * 4 + bj2;
#pragma unroll
      for (int r = 0; r < 4; ++r) {
        float pv = exp2f(s_acc[bj][r]);
        l_part[r] += pv;
        Ps[(wave * 16 + quad * 4 + r) * PST + bj2 * 16 + l15] = f2bf_fast(pv);
      }
    }
#pragma unroll
    for (int kk2 = 0; kk2 < 2; ++kk2) {
      bf16x8 pf = *(const bf16x8*)(&Ps[(wave * 16 + l15) * PST + kk2 * 32 + quad * 8]);
      int kk = ph * 2 + kk2;
#pragma unroll
      for (int dj = 0; dj < 4; ++dj) {
        bf16x8 vf = *(const bf16x8*)(&V[((kk * 4 + quad) * 64 + dj * 16 + l15) * 8]);
        o[dj] = __builtin_amdgcn_mfma_f32_16x16x32_bf16(pf, vf, o[dj], 0, 0, 0);
      }
    }
  }
}

// Q:(BH,S,64) pre-scaled bf16, K:(BH,S,64), Vt8:(BH,S/8,64,8).
// UNION-PAIRED: each block processes BOTH q-tiles (qp, 31-qp) in ONE pass over
// kt=0..(31-qp)/2 — the shared kt prefix is staged once (17 -> 9..16 staged
// tiles/block; compute stays balanced at 17 tile-units). GL2LDS double-buffer,
// one barrier per kt (R10, verified). bh in low 5 bits -> K/V XCD-local.
// Persistent state is accumulator-class (2x qf/o/l) — not the transient-load
// live ranges that spilled in R4/R7. launch_bounds(256,2): 256-VGPR budget.
__global__ __launch_bounds__(256, 2) void attn(const u16* __restrict__ Q,
                                               const u16* __restrict__ Kg,
                                               const u16* __restrict__ Vt8,
                                               u16* __restrict__ ctx) {
  __shared__ u16 Kd[2][128 * 64];
  __shared__ u16 Vd[2][64 * 128];
  __shared__ u16 Ps[64 * PST];
  const int tid = threadIdx.x;
  const int qp = blockIdx.x >> 5;   // 0..15
  const int bh = blockIdx.x & 31;   // 0..31
  const int wave = tid >> 6, lane = tid & 63;
  const int quad = lane >> 4, l15 = lane & 15;
  const size_t base = (size_t)bh * S_LEN * DHEAD;
  const int b = bh >> 4, h = bh & 15;
  const int xk7 = l15 & 7;

#define STAGE(kt_, pb)                                                                   \
  do {                                                                                   \
    _Pragma("unroll")                                                                    \
    for (int i_ = 0; i_ < 4; ++i_) {                                                     \
      int c_ = tid + 256 * i_;                                                           \
      int row_ = c_ >> 3, g_ = ((c_ & 7) ^ (row_ & 7)) * 8;                              \
      GL2LDS(Kg + base + (size_t)((kt_) * 128 + row_) * 64 + g_,                         \
             &Kd[pb][0] + i_ * 2048 + wave * 512);                                       \
      GL2LDS(Vt8 + base + (size_t)((kt_) * 1024 + c_) * 8,                               \
             &Vd[pb][0] + i_ * 2048 + wave * 512);                                       \
    }                                                                                    \
  } while (0)

  const int qtA = qp, qtB = 31 - qp;
  const int kmA = qtA >> 1, kmB = qtB >> 1;  // kmA <= kmB

  const int qrowA = qtA * 64 + wave * 16 + l15;
  const int qrowB = qtB * 64 + wave * 16 + l15;
  bf16x8 qfA0 = *(const bf16x8*)(Q + base + (size_t)qrowA * DHEAD + quad * 8);
  bf16x8 qfA1 = *(const bf16x8*)(Q + base + (size_t)qrowA * DHEAD + 32 + quad * 8);
  bf16x8 qfB0 = *(const bf16x8*)(Q + base + (size_t)qrowB * DHEAD + quad * 8);
  bf16x8 qfB1 = *(const bf16x8*)(Q + base + (size_t)qrowB * DHEAD + 32 + quad * 8);

  float lA[4] = {0.f, 0.f, 0.f, 0.f}, lB[4] = {0.f, 0.f, 0.f, 0.f};
  f32x4 oA[4] = {}, oB[4] = {};

  STAGE(0, 0);
  for (int kt = 0; kt <= kmB; ++kt) {
    const int p = kt & 1;
    __syncthreads();                        // drains this tile's deposits
    if (kt < kmB) STAGE(kt + 1, p ^ 1);     // overlaps all compute below

    if (kt <= kmA)
      attn_tile(qtA, kt, kmA, qfA0, qfA1, lA, oA, &Kd[p][0], &Vd[p][0], Ps,
                wave, quad, l15, xk7);
    attn_tile(qtB, kt, kmB, qfB0, qfB1, lB, oB, &Kd[p][0], &Vd[p][0], Ps,
              wave, quad, l15, xk7);
  }

  // epilogues: one cross-lane reduce per q-tile
#pragma unroll
  for (int e = 0; e < 2; ++e) {
    const int qt = e ? qtB : qtA;
    float* lp = e ? lB : lA;
    f32x4* op = e ? oB : oA;
#pragma unroll
    for (int r = 0; r < 4; ++r) {
      float s = lp[r];
      s += __shfl_xor(s, 1, 64);
      s += __shfl_xor(s, 2, 64);
      s += __shfl_xor(s, 4, 64);
      s += __shfl_xor(s, 8, 64);
      float inv = 1.0f / s;
      int srow = qt * 64 + wave * 16 + quad * 4 + r;
      size_t rowbase = ((size_t)b * S_LEN + srow) * DMODEL + h * DHEAD;
#pragma unroll
      for (int dj = 0; dj < 4; ++dj)
        ctx[rowbase + dj * 16 + l15] = f2bf(op[dj][r] * inv);
    }
  }
#undef STAGE
}

extern "C" void kernel_launch(void* const* d_in, const int* in_sizes, int n_in,
                              void* d_out, int out_size, void* d_ws, size_t ws_size,
                              hipStream_t stream) {
  const float* x  = (const float*)d_in[0];
  const float* Wq = (const float*)d_in[1];
  const float* bq = (const float*)d_in[2];
  const float* Wk = (const float*)d_in[3];
  const float* bk = (const float*)d_in[4];
  const float* Wv = (const float*)d_in[5];
  const float* bv = (const float*)d_in[6];
  const float* Wo = (const float*)d_in[7];
  const float* bo = (const float*)d_in[8];
  float* out = (float*)d_out;

  char* ws = (char*)d_ws;
  const size_t MB = 1u << 20;
  u16* xb   = (u16*)(ws + 0);        // 8 MB (reused as ctx after QKV GEMMs)
  u16* ctxb = xb;
  u16* wqb  = (u16*)(ws + 8 * MB);
  u16* wkb  = (u16*)(ws + 10 * MB);
  u16* wvb  = (u16*)(ws + 12 * MB);
  u16* wob  = (u16*)(ws + 14 * MB);
  u16* qb   = (u16*)(ws + 16 * MB);  // (B,H,S,DH) pre-scaled
  u16* kb   = (u16*)(ws + 24 * MB);  // (B,H,S,DH)
  u16* vtb  = (u16*)(ws + 32 * MB);  // Vt8 (B,H,S/8,DH,8)

  CvtArgs c;
  c.src[0] = x;  c.dst[0] = xb;
  c.src[1] = Wq; c.dst[1] = wqb;
  c.src[2] = Wk; c.dst[2] = wkb;
  c.src[3] = Wv; c.dst[3] = wvb;
  c.src[4] = Wo; c.dst[4] = wob;
  cvt_all<<<4096 + 4 * 1024, 256, 0, stream>>>(c);

  QKVArgs a;
  a.w[0] = wqb; a.w[1] = wkb; a.w[2] = wvb;
  a.b[0] = bq;  a.b[1] = bk;  a.b[2] = bv;
  a.o[0] = qb;  a.o[1] = kb;  a.o[2] = vtb;
  qkv_gemm<<<dim3(DMODEL / 128, MTOT / 128, 3), 256, 0, stream>>>(xb, a);

  attn<<<512, 256, 0, stream>>>(qb, kb, vtb, ctxb);

  out_gemm<<<dim3(DMODEL / 64, MTOT / 128), 256, 0, stream>>>(ctxb, wob, bo, out);
}